// Round 1
// baseline (81.014 us; speedup 1.0000x reference)
//
#include <hip/hip_runtime.h>
#include <stdint.h>

// UnfoldConv1d: y[b,o,t] = bias[o] + sum_j sum_c W[o, j*512+c] * x[b,c,t-2+j]
// B=8, C=512, T=4096, OUT=512, K=3, D=1.
// Strategy: bf16 MFMA GEMM. Prep: x -> transposed+padded bf16 xp_t[b][tp][c]
// (tp = t+2, TP=4104 rows, rows 0,1 and 4098..4103 are zeros), W -> bf16.
// GEMM: 128x128 tile, 4 waves (2x2), mfma_f32_16x16x32_bf16, single-buffer
// 2-barrier K-loop, global_load_lds staging with chunk-XOR swizzle.

typedef float    f32x4  __attribute__((ext_vector_type(4)));
typedef short    bf16x8 __attribute__((ext_vector_type(8)));

#define C_DIM   512
#define T_DIM   4096
#define TP_DIM  4104
#define OUT_DIM 512
#define KF_DIM  1536
#define B_DIM   8

__device__ __forceinline__ uint16_t f2bf(float f) {
  union { float f; uint32_t u; } v; v.f = f;
  uint32_t u = v.u;
  return (uint16_t)((u + 0x7fffu + ((u >> 16) & 1u)) >> 16);  // RNE
}

__device__ __forceinline__ void gload_lds16(const uint16_t* g, uint16_t* l) {
  __builtin_amdgcn_global_load_lds(
      (const __attribute__((address_space(1))) uint32_t*)g,
      (__attribute__((address_space(3))) uint32_t*)l, 16, 0, 0);
}

// ---------------- prep: W fp32 [512][1536] -> bf16 same layout ----------------
__global__ __launch_bounds__(256) void prep_w(const float* __restrict__ W,
                                              uint16_t* __restrict__ Wb) {
  int i = blockIdx.x * 256 + threadIdx.x;  // float4 units: 786432/4 = 196608
  if (i >= 196608) return;
  float4 v = ((const float4*)W)[i];
  ushort4 o;
  o.x = f2bf(v.x); o.y = f2bf(v.y); o.z = f2bf(v.z); o.w = f2bf(v.w);
  ((ushort4*)Wb)[i] = o;
}

// ------ prep: x fp32 [b][c][t] -> xp bf16 [b][tp][c], tp=t+2, TP=4104 --------
__global__ __launch_bounds__(256) void prep_x(const float* __restrict__ x,
                                              uint16_t* __restrict__ xp) {
  __shared__ uint16_t tile[64 * 66];  // [t_local][c_local], pad 66 vs banks
  const int tid = threadIdx.x;
  const int tp0 = blockIdx.x * 64;   // output row tile (65 tiles, last partial)
  const int c0  = blockIdx.y * 64;
  const int b   = blockIdx.z;
  // read phase: 64 c-rows x 32 float2 = 2048 units (coalesced along t)
  #pragma unroll
  for (int it = 0; it < 8; ++it) {
    int u = it * 256 + tid;
    int crow = u >> 5;            // 0..63
    int p = u & 31;               // float2 index along t
    int t = tp0 - 2 + p * 2;      // even; pair is fully valid or fully not
    float vx = 0.f, vy = 0.f;
    if (t >= 0 && t < T_DIM) {
      const float2 v = *(const float2*)(x + (long)(b * C_DIM + c0 + crow) * T_DIM + t);
      vx = v.x; vy = v.y;
    }
    tile[(2 * p) * 66 + crow]     = f2bf(vx);
    tile[(2 * p + 1) * 66 + crow] = f2bf(vy);
  }
  __syncthreads();
  // write phase: 64 t-rows x 32 ushort2 = 2048 units (coalesced along c)
  #pragma unroll
  for (int it = 0; it < 8; ++it) {
    int u = it * 256 + tid;
    int tl = u >> 5;
    int q = u & 31;
    int tp = tp0 + tl;
    if (tp < TP_DIM) {
      ushort2 val;
      val.x = tile[tl * 66 + 2 * q];
      val.y = tile[tl * 66 + 2 * q + 1];
      *(ushort2*)(xp + (long)(b * TP_DIM + tp) * C_DIM + c0 + 2 * q) = val;
    }
  }
}

// ---------------------------- main GEMM kernel -------------------------------
// grid (T/128=32, OUT/128=4, B=8), 256 threads, 4 waves as 2x2 of 64x64.
__global__ __launch_bounds__(256) void gemm_kernel(const uint16_t* __restrict__ xp,
                                                   const uint16_t* __restrict__ Wb,
                                                   const float* __restrict__ bias,
                                                   float* __restrict__ out) {
  __shared__ uint16_t XT[136 * 64];  // [row=tp_local 0..135][c 64], 128B rows, swizzled
  __shared__ uint16_t WS[128 * 64];  // [row=o_local][c 64], 128B rows, swizzled

  const int tid  = threadIdx.x;
  const int lane = tid & 63;
  const int wid  = tid >> 6;
  const int wm   = wid >> 1;     // wave row (0..1)
  const int wn   = wid & 1;      // wave col (0..1)
  const int t0 = blockIdx.x * 128;
  const int o0 = blockIdx.y * 128;
  const int b  = blockIdx.z;

  f32x4 acc[4][4];
  #pragma unroll
  for (int mi = 0; mi < 4; ++mi)
    #pragma unroll
    for (int ni = 0; ni < 4; ++ni)
      #pragma unroll
      for (int r = 0; r < 4; ++r) acc[mi][ni][r] = 0.0f;

  const uint16_t* xbase = xp + ((long)b * TP_DIM + t0) * C_DIM;
  const int g = lane >> 4;  // k-group 0..3 (8 consecutive k each)

  for (int c0 = 0; c0 < C_DIM; c0 += 64) {
    #pragma unroll
    for (int j = 0; j < 3; ++j) {
      __syncthreads();
      if (j == 0) {
        // stage XT: 136 rows x 8 chunks(16B) = 1088 units; src chunk pre-swizzled
        #pragma unroll
        for (int it = 0; it < 4; ++it) {
          int u = it * 256 + tid;
          int row = u >> 3, ch = u & 7;
          const uint16_t* src = xbase + (long)row * C_DIM + c0 + ((ch ^ (row & 7)) << 3);
          gload_lds16(src, &XT[(it * 256 + wid * 64) * 8]);
        }
        if (tid < 64) {
          int u = 1024 + tid;
          int row = u >> 3, ch = u & 7;
          const uint16_t* src = xbase + (long)row * C_DIM + c0 + ((ch ^ (row & 7)) << 3);
          gload_lds16(src, &XT[1024 * 8]);
        }
      }
      // stage WS for this j: 128 rows x 8 chunks = 1024 units
      {
        const uint16_t* wbase = Wb + (long)o0 * KF_DIM + j * C_DIM + c0;
        #pragma unroll
        for (int it = 0; it < 4; ++it) {
          int u = it * 256 + tid;
          int row = u >> 3, ch = u & 7;
          const uint16_t* src = wbase + (long)row * KF_DIM + ((ch ^ (row & 7)) << 3);
          gload_lds16(src, &WS[(it * 256 + wid * 64) * 8]);
        }
      }
      __syncthreads();

      #pragma unroll
      for (int cc = 0; cc < 2; ++cc) {
        bf16x8 af[4], bfr[4];
        #pragma unroll
        for (int mi = 0; mi < 4; ++mi) {
          int row = wm * 64 + mi * 16 + (lane & 15);
          int chs = (cc * 4 + g) ^ (row & 7);
          af[mi] = *(const bf16x8*)&WS[row * 64 + chs * 8];
        }
        #pragma unroll
        for (int ni = 0; ni < 4; ++ni) {
          int row = wn * 64 + ni * 16 + (lane & 15) + j;  // tp_local = tn + j
          int chs = (cc * 4 + g) ^ (row & 7);
          bfr[ni] = *(const bf16x8*)&XT[row * 64 + chs * 8];
        }
        #pragma unroll
        for (int mi = 0; mi < 4; ++mi)
          #pragma unroll
          for (int ni = 0; ni < 4; ++ni)
            acc[mi][ni] = __builtin_amdgcn_mfma_f32_16x16x32_bf16(
                af[mi], bfr[ni], acc[mi][ni], 0, 0, 0);
      }
    }
  }

  // epilogue: D layout col=lane&15 (t), row=(lane>>4)*4+r (o)  [m89-verified]
  #pragma unroll
  for (int mi = 0; mi < 4; ++mi) {
    int orow = o0 + wm * 64 + mi * 16 + (lane >> 4) * 4;
    #pragma unroll
    for (int ni = 0; ni < 4; ++ni) {
      int t = t0 + wn * 64 + ni * 16 + (lane & 15);
      float* op = out + ((long)b * OUT_DIM + orow) * T_DIM + t;
      #pragma unroll
      for (int r = 0; r < 4; ++r)
        op[(long)r * T_DIM] = acc[mi][ni][r] + bias[orow + r];
    }
  }
}

// ------------------------- naive fallback (no ws) ----------------------------
__global__ __launch_bounds__(256) void naive_kernel(const float* __restrict__ x,
                                                    const float* __restrict__ W,
                                                    const float* __restrict__ bias,
                                                    float* __restrict__ y) {
  int t = blockIdx.x * 256 + threadIdx.x;
  int o = blockIdx.y, b = blockIdx.z;
  float s = bias[o];
  #pragma unroll
  for (int j = 0; j < 3; ++j) {
    int tt = t - 2 + j;
    if (tt < 0) continue;
    const float* xr = x + (long)b * C_DIM * T_DIM + tt;
    const float* wr = W + (long)o * KF_DIM + j * C_DIM;
    float a = 0.f;
    for (int c = 0; c < C_DIM; ++c) a += wr[c] * xr[(long)c * T_DIM];
    s += a;
  }
  y[((long)b * OUT_DIM + o) * T_DIM + t] = s;
}

extern "C" void kernel_launch(void* const* d_in, const int* in_sizes, int n_in,
                              void* d_out, int out_size, void* d_ws, size_t ws_size,
                              hipStream_t stream) {
  (void)in_sizes; (void)n_in; (void)out_size;
  const float* x    = (const float*)d_in[0];
  const float* W    = (const float*)d_in[1];
  const float* bias = (const float*)d_in[2];
  float* out = (float*)d_out;

  const size_t wb_elems = (size_t)OUT_DIM * KF_DIM;          // 786432
  const size_t xp_elems = (size_t)B_DIM * TP_DIM * C_DIM;    // 16809984
  const size_t need = (wb_elems + xp_elems) * sizeof(uint16_t);

  if (ws_size < need) {  // insurance: slow but correct
    naive_kernel<<<dim3(T_DIM / 256, OUT_DIM, B_DIM), 256, 0, stream>>>(x, W, bias, out);
    return;
  }

  uint16_t* Wb = (uint16_t*)d_ws;
  uint16_t* xp = (uint16_t*)d_ws + wb_elems;

  prep_w<<<768, 256, 0, stream>>>(W, Wb);
  prep_x<<<dim3(65, 8, 8), 256, 0, stream>>>(x, xp);
  gemm_kernel<<<dim3(32, 4, 8), 256, 0, stream>>>(xp, Wb, bias, out);
}